// Round 6
// baseline (229.588 us; speedup 1.0000x reference)
//
#include <hip/hip_runtime.h>

// Problem constants
#define Bn  16
#define Ln  224
#define K1n 8192
#define Pn  16
#define LH  2            // L split into two halves (window-widening)
#define LROWS 112        // rows per half
#define KC  8            // k-chunks per (b,lh) in k_cross: 1024 cols each
#define RG  16           // rows per pipeline group in k_cross
#define NGc (LROWS / RG) // 7 groups
#define NCHUNK 16        // k-chunks per batch for k_h3 partials (512 k each)

typedef float f2 __attribute__((ext_vector_type(2)));

// ws layout (floats):
//   wsC    : [Bn*LH][K1n][Pn]  cross partials (16.8 MB)
//   wsY    : [Bn*LH][K1n]      ysq partials   (1.05 MB)
//   ws_sum : [Bn][NCHUNK][Pn]
//   ws_max : [Bn][NCHUNK][Pn]
//   ws_mid : [Bn][Pn]
// Every slot written by exactly one thread before being read -> safe under
// the harness's 0xAA ws poison, no zeroing, no atomics.
// Total ws footprint ~17.9 MB << the ~448 MiB workspace the harness fills.

// ---------------------------------------------------------------------------
// Kernel 1 (k_cross): partial cross/ysq over one L-half.
// Grid: 256 blocks = 16 b x 2 lh x 8 kc. 512 threads, float2 per thread ->
// each block reads a 4 KiB contiguous window per row visit (2x round 3's
// 2 KiB): amortizes DRAM row activations on the 32KB-strided y stream.
// nt loads keep y out of the cache-allocate path. No exp/csq here.
// ---------------------------------------------------------------------------
__global__ __launch_bounds__(512, 2) void k_cross(
    const float* __restrict__ y,      // [B, L, K1] f32
    const float* __restrict__ w3c,    // [1, L, P]  f32
    float* __restrict__ wsC,          // [B*LH][K1][P]
    float* __restrict__ wsY)          // [B*LH][K1]
{
    const int tid = threadIdx.x;
    const int b   = blockIdx.x >> 4;         // 0..15
    const int lh  = (blockIdx.x >> 3) & 1;   // 0..1
    const int kc  = blockIdx.x & 7;          // 0..7

    float cross0[Pn], cross1[Pn];
#pragma unroll
    for (int p = 0; p < Pn; ++p) { cross0[p] = 0.f; cross1[p] = 0.f; }
    float ysq0 = 0.f, ysq1 = 0.f;

    // thread owns k-pair kk = kc*1024 + 2*tid (+1)
    const float* ybase = y + (size_t)b * Ln * K1n
                           + (size_t)lh * LROWS * K1n + (kc << 10);
    const f2* yp = reinterpret_cast<const f2*>(ybase) + tid;

    // 16-row software pipeline (double-buffered), nontemporal float2 loads
    f2 v[RG], vn[RG];
#pragma unroll
    for (int j = 0; j < RG; ++j)
        v[j] = __builtin_nontemporal_load(yp + (size_t)j * (K1n / 2));

    for (int g = 0; g < NGc; ++g) {
        if (g < NGc - 1) {
#pragma unroll
            for (int j = 0; j < RG; ++j)
                vn[j] = __builtin_nontemporal_load(
                            yp + (size_t)((g + 1) * RG + j) * (K1n / 2));
        }
        // rows lh*112 + g*16 + j ; w3c index wave-uniform -> SGPR broadcast
        const float* wrow = w3c + (size_t)(lh * LROWS + g * RG) * Pn;
#pragma unroll
        for (int j = 0; j < RG; ++j) {
            ysq0 = fmaf(v[j].x, v[j].x, ysq0);
            ysq1 = fmaf(v[j].y, v[j].y, ysq1);
#pragma unroll
            for (int p = 0; p < Pn; ++p) {
                const float w = wrow[j * Pn + p];
                cross0[p] = fmaf(v[j].x, w, cross0[p]);
                cross1[p] = fmaf(v[j].y, w, cross1[p]);
            }
        }
        if (g < NGc - 1) {
#pragma unroll
            for (int j = 0; j < RG; ++j) v[j] = vn[j];
        }
    }

    // write partials: k=2t -> cross0[0..15], k=2t+1 -> cross1[0..15]
    // 128 B contiguous per thread; block's region 64 KB contiguous.
    const size_t kk = (size_t)(kc << 10) + 2 * tid;
    float4* wc4 = reinterpret_cast<float4*>(
        wsC + ((size_t)(b * LH + lh) * K1n + kk) * Pn);
    wc4[0] = make_float4(cross0[0],  cross0[1],  cross0[2],  cross0[3]);
    wc4[1] = make_float4(cross0[4],  cross0[5],  cross0[6],  cross0[7]);
    wc4[2] = make_float4(cross0[8],  cross0[9],  cross0[10], cross0[11]);
    wc4[3] = make_float4(cross0[12], cross0[13], cross0[14], cross0[15]);
    wc4[4] = make_float4(cross1[0],  cross1[1],  cross1[2],  cross1[3]);
    wc4[5] = make_float4(cross1[4],  cross1[5],  cross1[6],  cross1[7]);
    wc4[6] = make_float4(cross1[8],  cross1[9],  cross1[10], cross1[11]);
    wc4[7] = make_float4(cross1[12], cross1[13], cross1[14], cross1[15]);

    float2* wy2 = reinterpret_cast<float2*>(
        wsY + (size_t)(b * LH + lh) * K1n + kk);
    *wy2 = make_float2(ysq0, ysq1);
}

// ---------------------------------------------------------------------------
// Kernel 2 (k_h3): combine the two L-half partials, apply exp, reduce
// sum/max per (b, 512-k chunk), extract mid. Reads 17.8 MB (L3-resident).
// Grid: 256 blocks = 16 b x 16 chunks, 512 threads, one k per thread.
// ---------------------------------------------------------------------------
__global__ __launch_bounds__(512, 2) void k_h3(
    const float* __restrict__ w3c,    // [1, L, P]  f32
    const float* __restrict__ sigma,  // [1]        f32
    const float* __restrict__ wsC,
    const float* __restrict__ wsY,
    float* __restrict__ ws_sum,
    float* __restrict__ ws_max,
    float* __restrict__ ws_mid)
{
    __shared__ float s_csq_part[32][Pn];
    __shared__ float s_csq[Pn];
    __shared__ float s_part_s[8][Pn];
    __shared__ float s_part_m[8][Pn];

    const int tid   = threadIdx.x;
    const int lane  = tid & 63;
    const int wv    = tid >> 6;          // 0..7
    const int b     = blockIdx.x >> 4;
    const int chunk = blockIdx.x & 15;
    const int k     = (chunk << 9) + tid;

    // c_sq[p] = sum_l w3c[l][p]^2 — cooperative prologue
    {
        const int p   = tid & 15;
        const int sub = tid >> 4;        // 0..31
        float cs = 0.f;
        for (int l = sub; l < Ln; l += 32) {
            float v = w3c[l * Pn + p];
            cs = fmaf(v, v, cs);
        }
        s_csq_part[sub][p] = cs;
    }
    __syncthreads();
    if (tid < Pn) {
        float cs = 0.f;
#pragma unroll
        for (int s = 0; s < 32; ++s) cs += s_csq_part[s][tid];
        s_csq[tid] = cs;
    }
    __syncthreads();

    // combine cross/ysq from the two L-halves (64 B x2 per thread, coalesced)
    const float4* q0 = reinterpret_cast<const float4*>(
        wsC + ((size_t)(b * LH + 0) * K1n + k) * Pn);
    const float4* q1 = reinterpret_cast<const float4*>(
        wsC + ((size_t)(b * LH + 1) * K1n + k) * Pn);
    float4 t0 = q0[0], t1 = q0[1], t2 = q0[2], t3 = q0[3];
    float4 u0 = q1[0], u1 = q1[1], u2 = q1[2], u3 = q1[3];

    float cr[Pn];
    cr[0]  = t0.x + u0.x; cr[1]  = t0.y + u0.y; cr[2]  = t0.z + u0.z; cr[3]  = t0.w + u0.w;
    cr[4]  = t1.x + u1.x; cr[5]  = t1.y + u1.y; cr[6]  = t1.z + u1.z; cr[7]  = t1.w + u1.w;
    cr[8]  = t2.x + u2.x; cr[9]  = t2.y + u2.y; cr[10] = t2.z + u2.z; cr[11] = t2.w + u2.w;
    cr[12] = t3.x + u3.x; cr[13] = t3.y + u3.y; cr[14] = t3.z + u3.z; cr[15] = t3.w + u3.w;

    const float ysq = wsY[(size_t)(b * LH + 0) * K1n + k]
                    + wsY[(size_t)(b * LH + 1) * K1n + k];

    const float sg = sigma[0];
    const float nh = -0.5f / (sg * sg);

    float h3[Pn];
#pragma unroll
    for (int p = 0; p < Pn; ++p) {
        float d = fmaxf(ysq + s_csq[p] - 2.f * cr[p], 0.f);
        h3[p] = __expf(d * nh);
    }

    // mid = h3[b, p, K1/2] : k == 4096 -> chunk == 8, tid == 0
    if (chunk == 8 && tid == 0) {
#pragma unroll
        for (int p = 0; p < Pn; ++p) ws_mid[b * Pn + p] = h3[p];
    }

    // Wave-level reduce (sum & max) per p, then cross-wave via LDS (8 waves)
#pragma unroll
    for (int p = 0; p < Pn; ++p) {
        float s = h3[p];
        float m = h3[p];
#pragma unroll
        for (int off = 32; off > 0; off >>= 1) {
            s += __shfl_down(s, off, 64);
            m = fmaxf(m, __shfl_down(m, off, 64));
        }
        if (lane == 0) { s_part_s[wv][p] = s; s_part_m[wv][p] = m; }
    }
    __syncthreads();
    if (tid < Pn) {
        float s = 0.f, m = -1.f;
#pragma unroll
        for (int w = 0; w < 8; ++w) {
            s += s_part_s[w][tid];
            m = fmaxf(m, s_part_m[w][tid]);
        }
        const int base = (b * NCHUNK + chunk) * Pn + tid;
        ws_sum[base] = s;
        ws_max[base] = m;
    }
}

// ---------------------------------------------------------------------------
// Kernel 3 (k_out): reduce partials + tiny finalize + out = h4 + w3_w@(a-d2).
// Identical to the round-3 (200.1 us) version.
// ---------------------------------------------------------------------------
__global__ __launch_bounds__(512, 2) void k_out(
    const float* __restrict__ a,      // [B, P, K1] f32
    const float* __restrict__ d2,     // [B, P, K1] f32
    const float* __restrict__ w3w,    // [P, P] f32
    const float* __restrict__ b3w,    // [P, P] f32
    const float* __restrict__ caw,    // [2, P] f32
    const float* __restrict__ ws_sum,
    const float* __restrict__ ws_max,
    const float* __restrict__ ws_mid,
    float* __restrict__ out)          // [B, P, K1] f32
{
    __shared__ float s_red_s[NCHUNK][Pn];
    __shared__ float s_red_m[NCHUNK][Pn];
    __shared__ float s_avg[Pn], s_mx[Pn], s_mid[Pn], s_h4[Pn];
    __shared__ float s_t[2];

    const int tid = threadIdx.x;
    const int b   = blockIdx.x >> 4;
    const int kb  = (blockIdx.x & 15) << 9;   // 512 k per block, 1 per thread

    // Issue the big streaming loads first — in flight across the finalize.
    const float* ap = a  + (size_t)b * Pn * K1n + kb + tid;
    const float* dp = d2 + (size_t)b * Pn * K1n + kb + tid;
    float av[Pn], dv[Pn];
#pragma unroll
    for (int q = 0; q < Pn; ++q) av[q] = ap[(size_t)q * K1n];
#pragma unroll
    for (int q = 0; q < Pn; ++q) dv[q] = dp[(size_t)q * K1n];

    // Parallel partial-load: threads 0..255 fetch the 16x16 ws partials
    if (tid < 256) {
        const int p   = tid & 15;
        const int grp = tid >> 4;          // 0..15
        const int i0  = (b * NCHUNK + grp) * Pn + p;
        s_red_s[grp][p] = ws_sum[i0];
        s_red_m[grp][p] = ws_max[i0];
    }
    __syncthreads();
    if (tid < Pn) {
        float s = 0.f, m = -1.f;
#pragma unroll
        for (int g = 0; g < NCHUNK; ++g) {
            s += s_red_s[g][tid];
            m = fmaxf(m, s_red_m[g][tid]);
        }
        s_avg[tid] = s * (1.f / (float)K1n);
        s_mx[tid]  = m;
        s_mid[tid] = ws_mid[b * Pn + tid];
    }
    __syncthreads();

    if (tid < 2) {
        float t1 = 0.f, t2 = 0.f;
        for (int p = 0; p < Pn; ++p) {
            float cw = caw[tid * Pn + p];
            t1 = fmaf(cw, s_avg[p], t1);
            t2 = fmaf(cw, s_mx[p],  t2);
        }
        t1 = (t1 > 0.f) ? t1 : 0.01f * t1;   // leaky_relu
        t2 = (t2 > 0.f) ? t2 : 0.01f * t2;
        s_t[tid] = t1 + t2;
    }
    __syncthreads();

    if (tid < Pn) {
        float t0 = s_t[0], u1 = s_t[1];
        float mt = fmaxf(t0, u1);
        float e0 = __expf(t0 - mt), e1 = __expf(u1 - mt);
        float inv = 1.f / (e0 + e1);
        s_red_s[0][tid] = (e0 * inv) * s_mid[tid] + (e1 * inv) * s_avg[tid];
    }
    __syncthreads();

    if (tid < Pn) {
        float h = 0.f;
        for (int q = 0; q < Pn; ++q) h = fmaf(b3w[tid * Pn + q], s_red_s[0][q], h);
        s_h4[tid] = h;
    }
    __syncthreads();

    // out[b,p,k] = h4[p] + w3_w[p,:]·(a-d2)[b,:,k] ; w3w via SGPR (uniform)
    float diff[Pn];
#pragma unroll
    for (int q = 0; q < Pn; ++q) diff[q] = av[q] - dv[q];

    float* op = out + (size_t)b * Pn * K1n + kb + tid;
#pragma unroll
    for (int p = 0; p < Pn; ++p) {
        float h2 = s_h4[p];
#pragma unroll
        for (int q = 0; q < Pn; ++q)
            h2 = fmaf(w3w[p * Pn + q], diff[q], h2);
        op[(size_t)p * K1n] = h2;
    }
}

// ---------------------------------------------------------------------------
extern "C" void kernel_launch(void* const* d_in, const int* in_sizes, int n_in,
                              void* d_out, int out_size, void* d_ws, size_t ws_size,
                              hipStream_t stream) {
    const float* a     = (const float*)d_in[0];
    const float* d2    = (const float*)d_in[1];
    const float* y     = (const float*)d_in[2];
    const float* w3w   = (const float*)d_in[3];
    const float* b3w   = (const float*)d_in[4];
    const float* w3c   = (const float*)d_in[5];
    const float* sigma = (const float*)d_in[6];
    const float* caw   = (const float*)d_in[7];

    float* wsC    = (float*)d_ws;                       // [B*LH][K1][P]
    float* wsY    = wsC + (size_t)Bn * LH * K1n * Pn;   // [B*LH][K1]
    float* ws_sum = wsY + (size_t)Bn * LH * K1n;        // [B][16][P]
    float* ws_max = ws_sum + Bn * NCHUNK * Pn;
    float* ws_mid = ws_max + Bn * NCHUNK * Pn;

    k_cross<<<dim3(Bn * LH * KC), dim3(512), 0, stream>>>(
        y, w3c, wsC, wsY);

    k_h3<<<dim3(Bn * NCHUNK), dim3(512), 0, stream>>>(
        w3c, sigma, wsC, wsY, ws_sum, ws_max, ws_mid);

    k_out<<<dim3(Bn * NCHUNK), dim3(512), 0, stream>>>(
        a, d2, w3w, b3w, caw, ws_sum, ws_max, ws_mid, (float*)d_out);
}